// Round 7
// baseline (78.255 us; speedup 1.0000x reference)
//
#include <hip/hip_runtime.h>
#include <hip/hip_bf16.h>

namespace {

constexpr int kHW = 36864;  // 192*192
constexpr int kFocalQuads = 7744 * 20;  // 4 classes per thread

typedef __attribute__((ext_vector_type(8))) short bf16x8;
typedef __attribute__((ext_vector_type(4))) float f32x4;

__device__ __forceinline__ unsigned short f2bf(float x) {
  return __builtin_bit_cast(unsigned short, __float2bfloat16(x));
}

__device__ __forceinline__ float wave_sum(float v) {
#pragma unroll
  for (int off = 32; off; off >>= 1) v += __shfl_xor(v, off, 64);
  return v;
}

// ---------------------------------------------------------------------------
// Pre-gather: pick the 80 positive kernel rows per batch, convert to bf16,
// store densely as kbf[b][row80][256]. Grid (80, 2), block 128 (2 ch/thread).
// ---------------------------------------------------------------------------
__global__ __launch_bounds__(128) void gather_k(
    const float* __restrict__ k0, const float* __restrict__ k1,
    const float* __restrict__ k2, const float* __restrict__ k3,
    const float* __restrict__ k4,
    const int* __restrict__ q0, const int* __restrict__ q1,
    const int* __restrict__ q2, const int* __restrict__ q3,
    const int* __restrict__ q4,
    unsigned short* __restrict__ kbf) {
  const int b = blockIdx.y;
  const int row = blockIdx.x;  // 0..79
  const int l = row >> 4, p = row & 15;
  const float* kb[5] = {k0, k1, k2, k3, k4};
  const int* pb[5] = {q0, q1, q2, q3, q4};
  const int bg2[5] = {b * 1600, b * 1296, b * 576, b * 256, b * 144};
  const int pos = pb[l][b * 16 + p];
  const int ch = threadIdx.x * 2;
  const float2 kv = *(const float2*)(kb[l] + (size_t)(bg2[l] + pos) * 256 + ch);
  *(unsigned int*)&kbf[((size_t)b * 80 + row) * 256 + ch] =
      (unsigned int)f2bf(kv.x) | ((unsigned int)f2bf(kv.y) << 16);
}

// ---------------------------------------------------------------------------
// MFMA main kernel, m97-style staged B. Block = 256 thr (4 waves) owns 64 px
// x 80 rows; grid = (576, 2) = 1152 blocks. Per K-step (BK=32): async
// global_load_lds (width=16) stages a [32ch][64px] f32 tile (8 KB) into a
// double buffer; each wave builds its B-frag from LDS columns (ds_read_b32,
// 4-way bank alias = 1.58x, acceptable) + cvt to bf16; A-frags from the
// pre-gathered bf16 K (L1-resident 40 KB/batch); 5 MFMA per wave per step.
// Epilogue: sigmoid, mt gather, 16-lane shfl reduce, LDS block-reduce, one
// atomic per (row, quantity) per block.
// ---------------------------------------------------------------------------
__global__ __launch_bounds__(256, 2) void solov2_main(
    const float* __restrict__ mask_out,
    const unsigned short* __restrict__ kbf,
    const float* __restrict__ mask_targets,
    float* __restrict__ acc) {
  const int b = blockIdx.y;
  const int lane = threadIdx.x & 63;
  const int wv = threadIdx.x >> 6;
  const int px16 = lane & 15;
  const int hi8 = (lane >> 4) * 8;
  const int px0 = blockIdx.x * 64;
  const int pxl = px0 + wv * 16 + px16;

  __shared__ float bufB[2][32][64];  // [buf][ch][px] f32, 8 KB each
  __shared__ float bred[4][240];

  // A-frag base: row80 = mt*16 + px16, channels hi8.. (ushort units)
  const unsigned short* __restrict__ ka =
      kbf + ((size_t)b * 80 + px16) * 256 + hi8;

  // Staging source: thread covers ch = wv*4 + (lane>>4), px = (lane&15)*4.
  const float* __restrict__ gstage = mask_out + (size_t)b * 256 * kHW +
                                     (size_t)(wv * 4 + (lane >> 4)) * kHW +
                                     px0 + (lane & 15) * 4;

#define STAGE(CUR, KS)                                                       \
  {                                                                          \
    const float* gs = gstage + (size_t)(KS)*32 * kHW;                        \
    __builtin_amdgcn_global_load_lds(                                        \
        (const __attribute__((address_space(1))) unsigned int*)gs,           \
        (__attribute__((address_space(3))) unsigned int*)&bufB[CUR][wv * 4]  \
            [0],                                                             \
        16, 0, 0);                                                           \
    __builtin_amdgcn_global_load_lds(                                        \
        (const __attribute__((address_space(1))) unsigned int*)(gs +         \
                                                                16 * kHW),   \
        (__attribute__((address_space(3))) unsigned int*)&bufB[CUR][wv * 4 + \
                                                                   16][0],   \
        16, 0, 0);                                                           \
  }

  f32x4 a5[5];
#pragma unroll
  for (int mt = 0; mt < 5; ++mt) a5[mt] = (f32x4){0.f, 0.f, 0.f, 0.f};

  STAGE(0, 0);
  __syncthreads();  // drains vmcnt -> buf0 ready

#pragma unroll
  for (int ks = 0; ks < 8; ++ks) {
    if (ks + 1 < 8) STAGE((ks + 1) & 1, ks + 1);
    // --- compute from bufB[ks&1] ---
    float fb[8];
#pragma unroll
    for (int j = 0; j < 8; ++j) fb[j] = bufB[ks & 1][hi8 + j][wv * 16 + px16];
    bf16x8 bb;
#pragma unroll
    for (int j = 0; j < 8; ++j) bb[j] = (short)f2bf(fb[j]);
#pragma unroll
    for (int mt = 0; mt < 5; ++mt) {
      const bf16x8 af = *(const bf16x8*)(ka + mt * 4096 + ks * 32);
      a5[mt] =
          __builtin_amdgcn_mfma_f32_16x16x32_bf16(af, bb, a5[mt], 0, 0, 0);
    }
    __syncthreads();  // staged loads drained; everyone done with current buf
  }
#undef STAGE

  // --- dice epilogue ---
  // D layout (m89): col = lane&15 (pixel), row80 = mt*16 + (lane>>4)*4 + reg.
  // Global flat row r = (row80>>4)*32 + b*16 + (row80&15); pairs with
  // mask_targets flat row r.
#pragma unroll
  for (int mt = 0; mt < 5; ++mt) {
#pragma unroll
    for (int j = 0; j < 4; ++j) {
      const int row80 = mt * 16 + (lane >> 4) * 4 + j;
      const int r = (row80 >> 4) * 32 + b * 16 + (row80 & 15);
      const float x0 = a5[mt][j];
      const float mp = 1.f / (1.f + __expf(-x0));
      const float tv = mask_targets[(size_t)r * kHW + pxl];
      float av = mp * tv;
      float bv = mp * mp;
      float cv = tv;  // binary targets: t*t == t
#pragma unroll
      for (int m = 1; m <= 8; m <<= 1) {
        av += __shfl_xor(av, m, 64);
        bv += __shfl_xor(bv, m, 64);
        cv += __shfl_xor(cv, m, 64);
      }
      if (px16 == 0) {
        bred[wv][row80] = av;
        bred[wv][80 + row80] = bv;
        bred[wv][160 + row80] = cv;
      }
    }
  }
  __syncthreads();
  if (threadIdx.x < 240) {
    const int q = threadIdx.x / 80;
    const int row80 = threadIdx.x - q * 80;
    const int r = (row80 >> 4) * 32 + b * 16 + (row80 & 15);
    const float s = bred[0][threadIdx.x] + bred[1][threadIdx.x] +
                    bred[2][threadIdx.x] + bred[3][threadIdx.x];
    unsafeAtomicAdd(&acc[q * 160 + r], s);
  }
}

// ---------------------------------------------------------------------------
// Focal loss. One (cell, class-quad) per thread; float4 class loads.
// 7744 cells x 20 quads = 154880 threads = 605 blocks x 256.
// ---------------------------------------------------------------------------
__global__ __launch_bounds__(256) void focal_kernel(
    const float* __restrict__ c0, const float* __restrict__ c1,
    const float* __restrict__ c2, const float* __restrict__ c3,
    const float* __restrict__ c4,
    const int* __restrict__ t0, const int* __restrict__ t1,
    const int* __restrict__ t2, const int* __restrict__ t3,
    const int* __restrict__ t4,
    float* __restrict__ acc) {
  const int idx = blockIdx.x * 256 + threadIdx.x;  // < kFocalQuads exactly
  const int n = idx / 20;             // cell index in concat order
  const int cq = (idx - n * 20) * 4;  // first class of the quad
  int t;
  const float* crow;
  if (n < 3200) {
    t = t0[n]; crow = c0 + (size_t)n * 80;
  } else if (n < 5792) {
    const int o = n - 3200; t = t1[o]; crow = c1 + (size_t)o * 80;
  } else if (n < 6944) {
    const int o = n - 5792; t = t2[o]; crow = c2 + (size_t)o * 80;
  } else if (n < 7456) {
    const int o = n - 6944; t = t3[o]; crow = c3 + (size_t)o * 80;
  } else {
    const int o = n - 7456; t = t4[o]; crow = c4 + (size_t)o * 80;
  }
  float term = 0.f, np = 0.f;
  if (t > -1) {
    const float4 pv4 = *(const float4*)&crow[cq];
    const float pvs[4] = {pv4.x, pv4.y, pv4.z, pv4.w};
#pragma unroll
    for (int j = 0; j < 4; ++j) {
      float pv = fminf(fmaxf(pvs[j], 1e-4f), 1.f - 1e-4f);
      const bool gm = (cq + j == t);
      const float af = gm ? 0.25f : 0.75f;
      const float pt = gm ? pv : 1.f - pv;
      const float om = 1.f - pt;
      term = fmaf(af * om * om, -__logf(pt), term);
    }
    if (cq == 0) np = 1.f;
  }
  term = wave_sum(term);
  np = wave_sum(np);
  __shared__ float st[8];
  const int wid = threadIdx.x >> 6;
  if ((threadIdx.x & 63) == 0) {
    st[wid] = term;
    st[4 + wid] = np;
  }
  __syncthreads();
  if (threadIdx.x == 0) {
    unsafeAtomicAdd(&acc[480], st[0] + st[1] + st[2] + st[3]);
    unsafeAtomicAdd(&acc[481], st[4] + st[5] + st[6] + st[7]);
  }
}

__global__ void zero_kernel(float* __restrict__ acc) {
  const int i = blockIdx.x * 256 + threadIdx.x;
  if (i < 482) acc[i] = 0.f;
}

__global__ __launch_bounds__(64) void finalize_kernel(
    const float* __restrict__ acc, float* __restrict__ out) {
  const int tid = threadIdx.x;
  float s = 0.f;
#pragma unroll
  for (int rr = 0; rr < 3; ++rr) {
    const int r = tid + rr * 64;
    if (r < 160) {
      const float a = acc[r];
      const float bb = acc[160 + r];
      const float cc = acc[320 + r];
      s += 1.f - 2.f * a / (bb + cc + 1e-4f);
    }
  }
  s = wave_sum(s);
  if (tid == 0) {
    out[0] = 3.0f * (s / 160.f);   // MASK_W * mask_loss
    out[1] = acc[480] / acc[481];  // CLS_W * cls_loss
  }
}

}  // namespace

extern "C" void kernel_launch(void* const* d_in, const int* in_sizes, int n_in,
                              void* d_out, int out_size, void* d_ws,
                              size_t ws_size, hipStream_t stream) {
  const float* mask_out = (const float*)d_in[0];
  const float* k[5];
  const float* cc[5];
  const int* pp[5];
  const int* tt[5];
  for (int i = 0; i < 5; ++i) {
    k[i] = (const float*)d_in[1 + 4 * i];
    cc[i] = (const float*)d_in[2 + 4 * i];
    pp[i] = (const int*)d_in[3 + 4 * i];
    tt[i] = (const int*)d_in[4 + 4 * i];
  }
  const float* mt = (const float*)d_in[21];
  float* acc = (float*)d_ws;                                    // 482 floats
  unsigned short* kbf = (unsigned short*)((float*)d_ws + 512);  // 80KB bf16
  float* out = (float*)d_out;

  hipLaunchKernelGGL(zero_kernel, dim3(2), dim3(256), 0, stream, acc);
  hipLaunchKernelGGL(gather_k, dim3(80, 2), dim3(128), 0, stream, k[0], k[1],
                     k[2], k[3], k[4], pp[0], pp[1], pp[2], pp[3], pp[4], kbf);
  hipLaunchKernelGGL(solov2_main, dim3(576, 2), dim3(256), 0, stream, mask_out,
                     kbf, mt, acc);
  hipLaunchKernelGGL(focal_kernel, dim3(605), dim3(256), 0, stream, cc[0],
                     cc[1], cc[2], cc[3], cc[4], tt[0], tt[1], tt[2], tt[3],
                     tt[4], acc);
  hipLaunchKernelGGL(finalize_kernel, dim3(1), dim3(64), 0, stream, acc, out);
}

// Round 8
// 70.033 us; speedup vs baseline: 1.1174x; 1.1174x over previous
//
#include <hip/hip_runtime.h>
#include <hip/hip_bf16.h>

namespace {

constexpr int kHW = 36864;  // 192*192
constexpr int kGemmBlocks = 1152;       // 576 px-tiles x 2 batches
constexpr int kFocalBlocks = 605;       // 7744 cells x 20 quads / 256

typedef __attribute__((ext_vector_type(8))) short bf16x8;
typedef __attribute__((ext_vector_type(4))) float f32x4;

__device__ __forceinline__ unsigned short f2bf(float x) {
  return __builtin_bit_cast(unsigned short, __float2bfloat16(x));
}

__device__ __forceinline__ float wave_sum(float v) {
#pragma unroll
  for (int off = 32; off; off >>= 1) v += __shfl_xor(v, off, 64);
  return v;
}

// ---------------------------------------------------------------------------
// Prep: block 0 zeroes acc[0..481]; blocks 1..160 gather one positive kernel
// row each (batch b, row80) into dense bf16 kbf[b][row80][256].
// ---------------------------------------------------------------------------
__global__ __launch_bounds__(256) void prep_kernel(
    const float* __restrict__ k0, const float* __restrict__ k1,
    const float* __restrict__ k2, const float* __restrict__ k3,
    const float* __restrict__ k4,
    const int* __restrict__ q0, const int* __restrict__ q1,
    const int* __restrict__ q2, const int* __restrict__ q3,
    const int* __restrict__ q4,
    unsigned short* __restrict__ kbf, float* __restrict__ acc) {
  const int bid = blockIdx.x;
  if (bid == 0) {
    for (int i = threadIdx.x; i < 482; i += 256) acc[i] = 0.f;
    return;
  }
  const int idx = bid - 1;
  const int b = idx / 80;
  const int row = idx - b * 80;
  if (threadIdx.x >= 128) return;
  const int l = row >> 4, p = row & 15;
  const float* kb[5] = {k0, k1, k2, k3, k4};
  const int* pb[5] = {q0, q1, q2, q3, q4};
  const int bg2[5] = {b * 1600, b * 1296, b * 576, b * 256, b * 144};
  const int pos = pb[l][b * 16 + p];
  const int ch = threadIdx.x * 2;
  const float2 kv = *(const float2*)(kb[l] + (size_t)(bg2[l] + pos) * 256 + ch);
  *(unsigned int*)&kbf[((size_t)b * 80 + row) * 256 + ch] =
      (unsigned int)f2bf(kv.x) | ((unsigned int)f2bf(kv.y) << 16);
}

// ---------------------------------------------------------------------------
// Mega kernel. Blocks [0,1152): MFMA GEMM + dice. Blocks [1152,1757): focal.
//
// GEMM part: block = 256 thr (4 waves), 64 px x 80 rows, K=256 in 4 BK=64
// steps. Double-buffered LDS stage via global_load_lds width=16 (4 issues per
// step per thread -> deeper in-flight queue, 4 barrier drains instead of 8).
// A-frags from dense bf16 kbf (L2-hot). Epilogue: sigmoid + mt + 16-lane
// shuffle reduce + LDS block reduce + 240 atomics.
// ---------------------------------------------------------------------------
__global__ __launch_bounds__(256, 2) void mega_kernel(
    const float* __restrict__ mask_out,
    const unsigned short* __restrict__ kbf,
    const float* __restrict__ mask_targets,
    const float* __restrict__ c0, const float* __restrict__ c1,
    const float* __restrict__ c2, const float* __restrict__ c3,
    const float* __restrict__ c4,
    const int* __restrict__ t0, const int* __restrict__ t1,
    const int* __restrict__ t2, const int* __restrict__ t3,
    const int* __restrict__ t4,
    float* __restrict__ acc) {
  __shared__ float bufB[2][64][64];  // 32 KB: [buf][ch][px] f32
  __shared__ float bred[4][240];     // 3.75 KB

  const int bid = blockIdx.x;

  if (bid >= kGemmBlocks) {
    // ---------------- focal loss tail blocks ----------------
    const int idx = (bid - kGemmBlocks) * 256 + threadIdx.x;  // < 154880
    const int n = idx / 20;             // cell index in concat order
    const int cq = (idx - n * 20) * 4;  // first class of the quad
    int t;
    const float* crow;
    if (n < 3200) {
      t = t0[n]; crow = c0 + (size_t)n * 80;
    } else if (n < 5792) {
      const int o = n - 3200; t = t1[o]; crow = c1 + (size_t)o * 80;
    } else if (n < 6944) {
      const int o = n - 5792; t = t2[o]; crow = c2 + (size_t)o * 80;
    } else if (n < 7456) {
      const int o = n - 6944; t = t3[o]; crow = c3 + (size_t)o * 80;
    } else {
      const int o = n - 7456; t = t4[o]; crow = c4 + (size_t)o * 80;
    }
    float term = 0.f, np = 0.f;
    if (t > -1) {
      const float4 pv4 = *(const float4*)&crow[cq];
      const float pvs[4] = {pv4.x, pv4.y, pv4.z, pv4.w};
#pragma unroll
      for (int j = 0; j < 4; ++j) {
        float pv = fminf(fmaxf(pvs[j], 1e-4f), 1.f - 1e-4f);
        const bool gm = (cq + j == t);
        const float af = gm ? 0.25f : 0.75f;
        const float pt = gm ? pv : 1.f - pv;
        const float om = 1.f - pt;
        term = fmaf(af * om * om, -__logf(pt), term);
      }
      if (cq == 0) np = 1.f;
    }
    term = wave_sum(term);
    np = wave_sum(np);
    const int wid = threadIdx.x >> 6;
    if ((threadIdx.x & 63) == 0) {
      bred[0][wid] = term;
      bred[0][4 + wid] = np;
    }
    __syncthreads();
    if (threadIdx.x == 0) {
      unsafeAtomicAdd(&acc[480],
                      bred[0][0] + bred[0][1] + bred[0][2] + bred[0][3]);
      unsafeAtomicAdd(&acc[481],
                      bred[0][4] + bred[0][5] + bred[0][6] + bred[0][7]);
    }
    return;
  }

  // ---------------- GEMM + dice blocks ----------------
  const int b = bid / 576;
  const int tile = bid - b * 576;
  const int px0 = tile * 64;
  const int lane = threadIdx.x & 63;
  const int wv = threadIdx.x >> 6;
  const int px16 = lane & 15;
  const int hi8 = (lane >> 4) * 8;
  const int pxl = px0 + wv * 16 + px16;

  // A-frag base: row80 = mt*16 + px16, channel offset hi8 (ushort units)
  const unsigned short* __restrict__ ka =
      kbf + ((size_t)b * 80 + px16) * 256 + hi8;

  // Staging source: thread covers ch = (issue*16) + wv*4 + (lane>>4),
  // px = (lane&15)*4. Each wave-instruction fills 4 consecutive ch rows.
  const float* __restrict__ gstage = mask_out + (size_t)b * 256 * kHW +
                                     (size_t)(wv * 4 + (lane >> 4)) * kHW +
                                     px0 + (lane & 15) * 4;

#define STAGE(CUR, T)                                                        \
  {                                                                          \
    _Pragma("unroll") for (int r = 0; r < 4; ++r) {                          \
      const float* gs = gstage + (size_t)((T)*64 + r * 16) * kHW;            \
      __builtin_amdgcn_global_load_lds(                                      \
          (const __attribute__((address_space(1))) unsigned int*)gs,         \
          (__attribute__((address_space(3))) unsigned int*)                  \
              &bufB[CUR][r * 16 + wv * 4][0],                                \
          16, 0, 0);                                                         \
    }                                                                        \
  }

  f32x4 a5[5];
#pragma unroll
  for (int mt = 0; mt < 5; ++mt) a5[mt] = (f32x4){0.f, 0.f, 0.f, 0.f};

  STAGE(0, 0);
  __syncthreads();  // buf0 ready

#pragma unroll
  for (int t = 0; t < 4; ++t) {
    if (t + 1 < 4) STAGE((t + 1) & 1, t + 1);
#pragma unroll
    for (int sub = 0; sub < 2; ++sub) {
      const int ks = t * 2 + sub;
      float fb[8];
#pragma unroll
      for (int j = 0; j < 8; ++j)
        fb[j] = bufB[t & 1][sub * 32 + hi8 + j][wv * 16 + px16];
      bf16x8 bb;
#pragma unroll
      for (int j = 0; j < 8; ++j) bb[j] = (short)f2bf(fb[j]);
#pragma unroll
      for (int mt = 0; mt < 5; ++mt) {
        const bf16x8 af = *(const bf16x8*)(ka + mt * 4096 + ks * 32);
        a5[mt] =
            __builtin_amdgcn_mfma_f32_16x16x32_bf16(af, bb, a5[mt], 0, 0, 0);
      }
    }
    __syncthreads();  // next buf staged; everyone done reading current
  }
#undef STAGE

  // --- dice epilogue ---
  // D layout (m89): col = lane&15 (pixel), row80 = mt*16 + (lane>>4)*4 + reg.
  // Global flat row r = (row80>>4)*32 + b*16 + (row80&15); pairs with
  // mask_targets flat row r.
#pragma unroll
  for (int mt = 0; mt < 5; ++mt) {
#pragma unroll
    for (int j = 0; j < 4; ++j) {
      const int row80 = mt * 16 + (lane >> 4) * 4 + j;
      const int r = (row80 >> 4) * 32 + b * 16 + (row80 & 15);
      const float x0 = a5[mt][j];
      const float mp = 1.f / (1.f + __expf(-x0));
      const float tv = mask_targets[(size_t)r * kHW + pxl];
      float av = mp * tv;
      float bv = mp * mp;
      float cv = tv;  // binary targets: t*t == t
#pragma unroll
      for (int m = 1; m <= 8; m <<= 1) {
        av += __shfl_xor(av, m, 64);
        bv += __shfl_xor(bv, m, 64);
        cv += __shfl_xor(cv, m, 64);
      }
      if (px16 == 0) {
        bred[wv][row80] = av;
        bred[wv][80 + row80] = bv;
        bred[wv][160 + row80] = cv;
      }
    }
  }
  __syncthreads();
  if (threadIdx.x < 240) {
    const int q = threadIdx.x / 80;
    const int row80 = threadIdx.x - q * 80;
    const int r = (row80 >> 4) * 32 + b * 16 + (row80 & 15);
    const float s = bred[0][threadIdx.x] + bred[1][threadIdx.x] +
                    bred[2][threadIdx.x] + bred[3][threadIdx.x];
    unsafeAtomicAdd(&acc[q * 160 + r], s);
  }
}

__global__ __launch_bounds__(64) void finalize_kernel(
    const float* __restrict__ acc, float* __restrict__ out) {
  const int tid = threadIdx.x;
  float s = 0.f;
#pragma unroll
  for (int rr = 0; rr < 3; ++rr) {
    const int r = tid + rr * 64;
    if (r < 160) {
      const float a = acc[r];
      const float bb = acc[160 + r];
      const float cc = acc[320 + r];
      s += 1.f - 2.f * a / (bb + cc + 1e-4f);
    }
  }
  s = wave_sum(s);
  if (tid == 0) {
    out[0] = 3.0f * (s / 160.f);   // MASK_W * mask_loss
    out[1] = acc[480] / acc[481];  // CLS_W * cls_loss
  }
}

}  // namespace

extern "C" void kernel_launch(void* const* d_in, const int* in_sizes, int n_in,
                              void* d_out, int out_size, void* d_ws,
                              size_t ws_size, hipStream_t stream) {
  const float* mask_out = (const float*)d_in[0];
  const float* k[5];
  const float* cc[5];
  const int* pp[5];
  const int* tt[5];
  for (int i = 0; i < 5; ++i) {
    k[i] = (const float*)d_in[1 + 4 * i];
    cc[i] = (const float*)d_in[2 + 4 * i];
    pp[i] = (const int*)d_in[3 + 4 * i];
    tt[i] = (const int*)d_in[4 + 4 * i];
  }
  const float* mt = (const float*)d_in[21];
  float* acc = (float*)d_ws;                                    // 482 floats
  unsigned short* kbf = (unsigned short*)((float*)d_ws + 512);  // 80KB bf16
  float* out = (float*)d_out;

  hipLaunchKernelGGL(prep_kernel, dim3(161), dim3(256), 0, stream, k[0], k[1],
                     k[2], k[3], k[4], pp[0], pp[1], pp[2], pp[3], pp[4], kbf,
                     acc);
  hipLaunchKernelGGL(mega_kernel, dim3(kGemmBlocks + kFocalBlocks), dim3(256),
                     0, stream, mask_out, kbf, mt, cc[0], cc[1], cc[2], cc[3],
                     cc[4], tt[0], tt[1], tt[2], tt[3], tt[4], acc);
  hipLaunchKernelGGL(finalize_kernel, dim3(1), dim3(64), 0, stream, acc, out);
}